// Round 4
// baseline (233.189 us; speedup 1.0000x reference)
//
#include <hip/hip_runtime.h>

// Conditional InstanceNorm2d: x[B=32,C=256,H=64,W=64] fp32, style_id[B] int32,
// gamma/beta[S=16,C=256] fp32 -> out fp32.
//
// Dtype forensics (R1-R3): reading inputs as bf16 -> NaN (fp32 mantissa halves
// produce 0xFF-exponent patterns); runtime detector (R3) confirmed x/gamma/beta
// are full-mantissa fp32 and style_id int32; writing bf16 output failed with a
// finite ~16 error == packed-bf16-read-as-fp32 garbage => output is fp32.
//
// One block per (b,c) instance (grid=8192). 4096 spatial elems; 256 threads x
// 16 elems kept in registers between reduction and normalize+store:
// read x once (128 MiB) + write out once (128 MiB) -> ~41 us at 6.3 TB/s.

#define HW   4096
#define NC   256
#define NTHR 256

__global__ __launch_bounds__(NTHR) void cin2d_kernel(
    const float* __restrict__ x,
    const int* __restrict__ style_id,
    const float* __restrict__ gamma,
    const float* __restrict__ beta,
    float* __restrict__ out)
{
    const int inst = blockIdx.x;        // inst = b*NC + c
    const int b = inst >> 8;
    const int c = inst & (NC - 1);
    const int tid = threadIdx.x;

    const float4* xp4 = (const float4*)(x + (size_t)inst * HW);
    float4 f0 = xp4[tid];
    float4 f1 = xp4[tid + NTHR];
    float4 f2 = xp4[tid + 2 * NTHR];
    float4 f3 = xp4[tid + 3 * NTHR];

    float v[16];
    v[0]  = f0.x; v[1]  = f0.y; v[2]  = f0.z; v[3]  = f0.w;
    v[4]  = f1.x; v[5]  = f1.y; v[6]  = f1.z; v[7]  = f1.w;
    v[8]  = f2.x; v[9]  = f2.y; v[10] = f2.z; v[11] = f2.w;
    v[12] = f3.x; v[13] = f3.y; v[14] = f3.z; v[15] = f3.w;

    float s = 0.0f, q = 0.0f;
#pragma unroll
    for (int i = 0; i < 16; ++i) {
        s += v[i];
        q = fmaf(v[i], v[i], q);
    }

    // Wave(64) down-reduction
#pragma unroll
    for (int off = 32; off > 0; off >>= 1) {
        s += __shfl_down(s, off, 64);
        q += __shfl_down(q, off, 64);
    }

    __shared__ float ssum[4];
    __shared__ float ssq[4];
    const int wave = tid >> 6;
    const int lane = tid & 63;
    if (lane == 0) { ssum[wave] = s; ssq[wave] = q; }
    __syncthreads();

    float tot_s = ssum[0] + ssum[1] + ssum[2] + ssum[3];
    float tot_q = ssq[0] + ssq[1] + ssq[2] + ssq[3];

    const float inv_n = 1.0f / (float)HW;
    float mean = tot_s * inv_n;
    float var = fmaf(-mean, mean, tot_q * inv_n);
    var = var < 0.0f ? 0.0f : var;
    float rstd = rsqrtf(var + 1e-5f);

    // style-indexed affine (tiny, L1/L2-resident broadcast loads)
    int sid = style_id[b];
    float g  = gamma[sid * NC + c];
    float be = beta[sid * NC + c];

    float scale = g * rstd;
    float shift = fmaf(-mean, scale, be);

    float4* op4 = (float4*)(out + (size_t)inst * HW);
    float4 w;
    w.x = fmaf(v[0],  scale, shift);
    w.y = fmaf(v[1],  scale, shift);
    w.z = fmaf(v[2],  scale, shift);
    w.w = fmaf(v[3],  scale, shift);
    op4[tid] = w;
    w.x = fmaf(v[4],  scale, shift);
    w.y = fmaf(v[5],  scale, shift);
    w.z = fmaf(v[6],  scale, shift);
    w.w = fmaf(v[7],  scale, shift);
    op4[tid + NTHR] = w;
    w.x = fmaf(v[8],  scale, shift);
    w.y = fmaf(v[9],  scale, shift);
    w.z = fmaf(v[10], scale, shift);
    w.w = fmaf(v[11], scale, shift);
    op4[tid + 2 * NTHR] = w;
    w.x = fmaf(v[12], scale, shift);
    w.y = fmaf(v[13], scale, shift);
    w.z = fmaf(v[14], scale, shift);
    w.w = fmaf(v[15], scale, shift);
    op4[tid + 3 * NTHR] = w;
}

extern "C" void kernel_launch(void* const* d_in, const int* in_sizes, int n_in,
                              void* d_out, int out_size, void* d_ws, size_t ws_size,
                              hipStream_t stream) {
    const float* x     = (const float*)d_in[0];
    const int*   sid   = (const int*)d_in[1];
    const float* gamma = (const float*)d_in[2];
    const float* beta  = (const float*)d_in[3];
    float* out = (float*)d_out;

    const int B = 32, C = 256;
    dim3 grid(B * C), block(NTHR);
    hipLaunchKernelGGL(cin2d_kernel, grid, block, 0, stream,
                       x, sid, gamma, beta, out);
}